// Round 10
// baseline (16997.273 us; speedup 1.0000x reference)
//
#include <hip/hip_runtime.h>

// ---------------------------------------------------------------------------
// 2-layer GRU (B=64,T=1024,D=256,H=512) + dense head. Persistent-RNN,
// DUAL-ROLE wgs: 32 wgs, wg j owns 16-unit hidden slice j of BOTH layers.
// Epoch e: L0 step t=e, then L1 step t1=e-1 (lag 1). ONE poll + ONE flag
// write per wg per epoch. Exchange via the R3/R5-PROVEN architected path:
// relaxed agent-scope atomics through MALL (no sc0 tricks, no fences, no
// election). Per-wg 128B flag lines (parallel writes, R3-proven). Weights:
// Wh0+Wh1 frags in 96KB dynamic LDS; Wi0+Wi1 frags in registers (1 wg/CU).
// ---------------------------------------------------------------------------

#define T_STEPS 1024
#define EPOCHS  (T_STEPS + 1)
#define NWG     32

typedef _Float16 f16x8 __attribute__((ext_vector_type(8)));
typedef float    f32x4 __attribute__((ext_vector_type(4)));

// ws layout (bytes)
#define H0_OFF   0          // h0[2][64][512] f16   131072
#define H1_OFF   131072     // h1[2][64][512] f16   131072
#define Y0_OFF   262144     // y0[2][64][512] f16   131072
#define FLAG_OFF 393216     // flags[32] u32, 128B stride (4096)
#define WS_ZERO  (393216 + 4096)
#define FLAG_STRIDE 32      // uints

__device__ __forceinline__ float sigm_f(float x) { return 1.0f / (1.0f + __expf(-x)); }
__device__ __forceinline__ float tanh_f(float x) { return 2.0f / (1.0f + __expf(-2.0f * x)) - 1.0f; }

__device__ __forceinline__ f32x4 mfma16(f16x8 a, f16x8 b, f32x4 c) {
    return __builtin_amdgcn_mfma_f32_16x16x32_f16(a, b, c, 0, 0, 0);
}
__device__ __forceinline__ f16x8 pack8(const float* src, int stride) {
    f16x8 r;
#pragma unroll
    for (int j = 0; j < 8; ++j) r[j] = (_Float16)src[j * stride];
    return r;
}

// device-coherent 16B fragment load as 2x8B relaxed agent atomics (R3-proven)
__device__ __forceinline__ f16x8 ld_frag_dev(const _Float16* p) {
    union { unsigned long long u[2]; f16x8 f; } cvt;
    cvt.u[0] = __hip_atomic_load((const unsigned long long*)p,
                                 __ATOMIC_RELAXED, __HIP_MEMORY_SCOPE_AGENT);
    cvt.u[1] = __hip_atomic_load((const unsigned long long*)(p + 4),
                                 __ATOMIC_RELAXED, __HIP_MEMORY_SCOPE_AGENT);
    return cvt.f;
}
// device-coherent f16 store (R3-proven)
__device__ __forceinline__ void st_dev_f16(_Float16* p, float v) {
    unsigned short b = __builtin_bit_cast(unsigned short, (_Float16)v);
    __hip_atomic_store((unsigned short*)p, b, __ATOMIC_RELAXED, __HIP_MEMORY_SCOPE_AGENT);
}

// producer: drain exchange stores to coherence point, wg-sync, post epoch flag
__device__ __forceinline__ void arrive(unsigned* flags, int role, unsigned done) {
    asm volatile("s_waitcnt vmcnt(0)" ::: "memory");
    __syncthreads();
    if (threadIdx.x == 0)
        __hip_atomic_store(&flags[role * FLAG_STRIDE], done,
                           __ATOMIC_RELAXED, __HIP_MEMORY_SCOPE_AGENT);
}
// consumer: wave0 lanes 0-31 poll one flag line each (scattered, parallel)
__device__ __forceinline__ void poll(const unsigned* flags, unsigned e,
                                     int wave, int lane) {
    if (wave == 0) {
        const bool active = lane < NWG;
        const unsigned* p = flags + (lane & (NWG - 1)) * FLAG_STRIDE;
        int guard = 0;
        for (;;) {
            unsigned v = active
                ? __hip_atomic_load(p, __ATOMIC_RELAXED, __HIP_MEMORY_SCOPE_AGENT)
                : e;
            if (__all(v >= e)) break;
            if (++guard > (1 << 20)) break;   // bounded: fail loud, never hang
        }
    }
    __syncthreads();
}

__global__ __launch_bounds__(256, 1) void gru_scan(
    const float* __restrict__ x,     // [64,1024,256]
    const float* __restrict__ Wi0, const float* __restrict__ bi0,
    const float* __restrict__ Wh0, const float* __restrict__ bhn0,
    const float* __restrict__ Wi1, const float* __restrict__ bi1,
    const float* __restrict__ Wh1, const float* __restrict__ bhn1,
    float* __restrict__ c0_out,      // [64,512]
    float* __restrict__ c1_out,      // [64,512]
    unsigned char* __restrict__ ws)
{
    extern __shared__ char smem[];
    uint4* ldsB0 = (uint4*)smem;            // 48 KB Wh0 frags (nt*16+kt)
    uint4* ldsB1 = ldsB0 + 48 * 64;         // 48 KB Wh1 frags

    const int tid  = threadIdx.x;
    const int wave = tid >> 6;
    const int lane = tid & 63;
    const int quad = lane >> 4;
    const int l16  = lane & 15;
    const int role = blockIdx.x;            // 0..31
    const int cslice = role * 16;

    _Float16* h0buf = (_Float16*)(ws + H0_OFF);
    _Float16* h1buf = (_Float16*)(ws + H1_OFF);
    _Float16* y0buf = (_Float16*)(ws + Y0_OFF);
    unsigned* flags = (unsigned*)(ws + FLAG_OFF);

    // ---- stage Wh0/Wh1 B-frags into LDS ----
    // B-frag (16x16x32): lane holds B[k = kt*32 + quad*8 + j][n = l16]
    for (int f = wave * 12; f < wave * 12 + 12; ++f) {
        int nt = f >> 4, kt = f & 15;
        ldsB0[f * 64 + lane] = __builtin_bit_cast(uint4,
            pack8(Wh0 + (kt * 32 + quad * 8) * 1536 + nt * 512 + cslice + l16, 1536));
        ldsB1[f * 64 + lane] = __builtin_bit_cast(uint4,
            pack8(Wh1 + (kt * 32 + quad * 8) * 1536 + nt * 512 + cslice + l16, 1536));
    }
    // ---- Wi0 (24 frags) + Wi1 (48 frags) in registers ----
    f16x8 wif0[24];
#pragma unroll
    for (int nt = 0; nt < 3; ++nt)
#pragma unroll
        for (int kt = 0; kt < 8; ++kt)
            wif0[nt * 8 + kt] = pack8(Wi0 + (kt * 32 + quad * 8) * 1536 + nt * 512 + cslice + l16, 1536);
    f16x8 wif1[48];
#pragma unroll
    for (int nt = 0; nt < 3; ++nt)
#pragma unroll
        for (int kt = 0; kt < 16; ++kt)
            wif1[nt * 16 + kt] = pack8(Wi1 + (kt * 32 + quad * 8) * 1536 + nt * 512 + cslice + l16, 1536);

    const float b0r = bi0[cslice + l16], b0z = bi0[512 + cslice + l16],
                b0n = bi0[1024 + cslice + l16], bh0 = bhn0[cslice + l16];
    const float b1r = bi1[cslice + l16], b1z = bi1[512 + cslice + l16],
                b1n = bi1[1024 + cslice + l16], bh1 = bhn1[cslice + l16];

    __syncthreads();

    float hs0[4] = {0.f, 0.f, 0.f, 0.f};
    float hs1[4] = {0.f, 0.f, 0.f, 0.f};
    const int rowA = wave * 16 + l16;
    const int rowC = wave * 16 + quad * 4;
    const int cu   = cslice + l16;

    for (int e = 0; e < EPOCHS; ++e) {
        // ---- x prefetch for L0 t=e (cached, barrier-independent) ----
        f16x8 xa[8];
        if (e < T_STEPS) {
            const float* px = x + (size_t)rowA * 262144 + e * 256 + quad * 8;
#pragma unroll
            for (int kt = 0; kt < 8; ++kt) {
                f32x4 x0 = *(const f32x4*)(px + kt * 32);
                f32x4 x1 = *(const f32x4*)(px + kt * 32 + 4);
                f16x8 a;
                a[0] = (_Float16)x0[0]; a[1] = (_Float16)x0[1]; a[2] = (_Float16)x0[2]; a[3] = (_Float16)x0[3];
                a[4] = (_Float16)x1[0]; a[5] = (_Float16)x1[1]; a[6] = (_Float16)x1[2]; a[7] = (_Float16)x1[3];
                xa[kt] = a;
            }
        }

        // ---- single poll per epoch: all peers completed epoch e-1 ----
        if (e > 0) poll(flags, (unsigned)e, wave, lane);

        // ================= L0: t = e =================
        if (e < T_STEPS) {
            const _Float16* hR = h0buf + (e & 1) * 32768;
            _Float16* hW = h0buf + ((e + 1) & 1) * 32768;
            _Float16* yW = y0buf + (e & 1) * 32768;

            f32x4 ax0 = {0,0,0,0}, ax1 = {0,0,0,0}, ax2 = {0,0,0,0};
#pragma unroll
            for (int kt = 0; kt < 8; ++kt) {
                ax0 = mfma16(xa[kt], wif0[kt], ax0);
                ax1 = mfma16(xa[kt], wif0[8 + kt], ax1);
                ax2 = mfma16(xa[kt], wif0[16 + kt], ax2);
            }
            f32x4 ah0 = {0,0,0,0}, ah1 = {0,0,0,0}, ah2 = {0,0,0,0};
#pragma unroll
            for (int kt = 0; kt < 16; ++kt) {
                f16x8 a = ld_frag_dev(hR + rowA * 512 + kt * 32 + quad * 8);
                ah0 = mfma16(a, __builtin_bit_cast(f16x8, ldsB0[(0 * 16 + kt) * 64 + lane]), ah0);
                ah1 = mfma16(a, __builtin_bit_cast(f16x8, ldsB0[(1 * 16 + kt) * 64 + lane]), ah1);
                ah2 = mfma16(a, __builtin_bit_cast(f16x8, ldsB0[(2 * 16 + kt) * 64 + lane]), ah2);
            }
#pragma unroll
            for (int i = 0; i < 4; ++i) {
                const int b = rowC + i;
                float r = sigm_f(ax0[i] + b0r + ah0[i]);
                float z = sigm_f(ax1[i] + b0z + ah1[i]);
                float n = tanh_f(ax2[i] + b0n + r * (ah2[i] + bh0));
                float hnew = (1.0f - z) * n + z * hs0[i];
                hs0[i] = hnew;
                st_dev_f16(&hW[b * 512 + cu], hnew);
                st_dev_f16(&yW[b * 512 + cu], tanh_f(hnew));
                if (e == T_STEPS - 1) c0_out[b * 512 + cu] = hnew;
            }
        }

        // ================= L1: t1 = e - 1 =================
        if (e >= 1) {
            const int t1 = e - 1;
            const _Float16* hR1 = h1buf + (t1 & 1) * 32768;
            _Float16* hW1 = h1buf + ((t1 + 1) & 1) * 32768;
            const _Float16* yR = y0buf + (t1 & 1) * 32768;  // written at epoch t1

            f32x4 ah0 = {0,0,0,0}, ah1 = {0,0,0,0}, ah2 = {0,0,0,0};
            f32x4 ax0 = {0,0,0,0}, ax1 = {0,0,0,0}, ax2 = {0,0,0,0};
#pragma unroll
            for (int kt = 0; kt < 16; ++kt) {
                f16x8 ah = ld_frag_dev(hR1 + rowA * 512 + kt * 32 + quad * 8);
                f16x8 ay = ld_frag_dev(yR + rowA * 512 + kt * 32 + quad * 8);
                ah0 = mfma16(ah, __builtin_bit_cast(f16x8, ldsB1[(0 * 16 + kt) * 64 + lane]), ah0);
                ah1 = mfma16(ah, __builtin_bit_cast(f16x8, ldsB1[(1 * 16 + kt) * 64 + lane]), ah1);
                ah2 = mfma16(ah, __builtin_bit_cast(f16x8, ldsB1[(2 * 16 + kt) * 64 + lane]), ah2);
                ax0 = mfma16(ay, wif1[0 * 16 + kt], ax0);
                ax1 = mfma16(ay, wif1[1 * 16 + kt], ax1);
                ax2 = mfma16(ay, wif1[2 * 16 + kt], ax2);
            }
#pragma unroll
            for (int i = 0; i < 4; ++i) {
                const int b = rowC + i;
                float r = sigm_f(ax0[i] + b1r + ah0[i]);
                float z = sigm_f(ax1[i] + b1z + ah1[i]);
                float n = tanh_f(ax2[i] + b1n + r * (ah2[i] + bh1));
                float hnew = (1.0f - z) * n + z * hs1[i];
                hs1[i] = hnew;
                st_dev_f16(&hW1[b * 512 + cu], hnew);
                if (t1 == T_STEPS - 1) c1_out[b * 512 + cu] = hnew;
            }
        }

        if (e < EPOCHS - 1) arrive(flags, role, (unsigned)(e + 1));
    }
}

// out = tanh(tanh(c1) @ W_out + b_out) : [64,512]@[512,512] fp32
__global__ __launch_bounds__(256) void dense_out(
    const float* __restrict__ c1, const float* __restrict__ Wout,
    const float* __restrict__ bout, float* __restrict__ out)
{
    __shared__ float a[512];
    const int b = blockIdx.x, tid = threadIdx.x;
    a[tid]       = tanh_f(c1[b * 512 + tid]);
    a[tid + 256] = tanh_f(c1[b * 512 + tid + 256]);
    __syncthreads();
    float acc0 = 0.f, acc1 = 0.f;
#pragma unroll 4
    for (int k = 0; k < 512; ++k) {
        const float av = a[k];
        acc0 += av * Wout[k * 512 + tid];
        acc1 += av * Wout[k * 512 + tid + 256];
    }
    out[b * 512 + tid]       = tanh_f(acc0 + bout[tid]);
    out[b * 512 + tid + 256] = tanh_f(acc1 + bout[tid + 256]);
}

extern "C" void kernel_launch(void* const* d_in, const int* in_sizes, int n_in,
                              void* d_out, int out_size, void* d_ws, size_t ws_size,
                              hipStream_t stream)
{
    const float* x    = (const float*)d_in[0];
    const float* Wi0  = (const float*)d_in[1];
    const float* bi0  = (const float*)d_in[2];
    const float* Wh0  = (const float*)d_in[3];
    const float* bhn0 = (const float*)d_in[4];
    const float* Wi1  = (const float*)d_in[5];
    const float* bi1  = (const float*)d_in[6];
    const float* Wh1  = (const float*)d_in[7];
    const float* bhn1 = (const float*)d_in[8];
    const float* Wout = (const float*)d_in[9];
    const float* bout = (const float*)d_in[10];
    float* out = (float*)d_out;
    unsigned char* ws = (unsigned char*)d_ws;

    (void)hipFuncSetAttribute((const void*)gru_scan,
                              hipFuncAttributeMaxDynamicSharedMemorySize, 98304);

    // zero h/y buffers + flag lines (ws poisoned 0xAA each launch)
    (void)hipMemsetAsync(ws, 0, WS_ZERO, stream);

    gru_scan<<<NWG, 256, 98304, stream>>>(x, Wi0, bi0, Wh0, bhn0,
                                          Wi1, bi1, Wh1, bhn1,
                                          out + 32768, out + 65536, ws);
    dense_out<<<64, 256, 0, stream>>>(out + 65536, Wout, bout, out);
}